// Round 9
// baseline (59.384 us; speedup 1.0000x reference)
//
#include <hip/hip_runtime.h>

#define LQ    8500
#define C_DIM 256

typedef __attribute__((ext_vector_type(8))) short bf16x8;
typedef __attribute__((ext_vector_type(4))) float f32x4;
typedef __attribute__((ext_vector_type(8))) __bf16 bf8v;

__device__ __forceinline__ unsigned short f2bf(float x) {
    union { float f; unsigned u; } c; c.f = x;
    unsigned r = c.u + 0x7FFFu + ((c.u >> 16) & 1u);
    return (unsigned short)(r >> 16);
}
__device__ __forceinline__ float bf2f(unsigned us) {
    union { unsigned u; float f; } c; c.u = us << 16;
    return c.f;
}

// 8 f32 -> bf16x8 via native casts (compiler emits packed v_cvt_pk_bf16_f32)
__device__ __forceinline__ bf16x8 cvt8(f32x4 lo, f32x4 hi) {
    bf8v b;
    b[0] = (__bf16)lo[0]; b[1] = (__bf16)lo[1];
    b[2] = (__bf16)lo[2]; b[3] = (__bf16)lo[3];
    b[4] = (__bf16)hi[0]; b[5] = (__bf16)hi[1];
    b[6] = (__bf16)hi[2]; b[7] = (__bf16)hi[3];
    union { bf8v b; bf16x8 s; } u; u.b = b;
    return u.s;
}

__device__ __forceinline__ void gload_lds16(const void* g, void* l) {
    __builtin_amdgcn_global_load_lds(
        (const __attribute__((address_space(1))) unsigned int*)g,
        (__attribute__((address_space(3))) unsigned int*)l, 16, 0, 0);
}

// ---------------------------------------------------------------------------
// prep: weights only. Transpose+convert to bf16 [N][K]; concat off/attn
// weights (384 cols) and biases. ~0.9 MB total.
// ---------------------------------------------------------------------------
__global__ __launch_bounds__(256)
void prep_w(const float* __restrict__ Wv,   const float* __restrict__ Wout,
            const float* __restrict__ Woff, const float* __restrict__ Wattn,
            const float* __restrict__ boff, const float* __restrict__ battn,
            unsigned short* __restrict__ Wv_t, unsigned short* __restrict__ Wout_t,
            unsigned short* __restrict__ Wcat_t, float* __restrict__ bcat)
{
    const int total = 65536 * 3 + 32768 + 384;
    for (int i = blockIdx.x * 256 + threadIdx.x; i < total; i += gridDim.x * 256) {
        if (i < 65536) {
            int k = i >> 8, n = i & 255;
            Wv_t[n * 256 + k] = f2bf(Wv[i]);
        } else if (i < 131072) {
            int j = i - 65536; int k = j >> 8, n = j & 255;
            Wout_t[n * 256 + k] = f2bf(Wout[j]);
        } else if (i < 196608) {
            int j = i - 131072; int k = j >> 8, n = j & 255;
            Wcat_t[n * 256 + k] = f2bf(Woff[j]);
        } else if (i < 229376) {
            int j = i - 196608; int k = j >> 7, n = j & 127;
            Wcat_t[(256 + n) * 256 + k] = f2bf(Wattn[j]);
        } else {
            int j = i - 229376;
            bcat[j] = (j < 256) ? boff[j] : battn[j - 256];
        }
    }
}

// ---------------------------------------------------------------------------
// MFMA GEMM body: Out[M x N] = A[M x 256] @ Bt^T + bias, Bt is [N][256] bf16.
// 64x64 tile, BK=64, 256 threads = 4 waves (2x2), each wave a 32x32 sub-tile.
// All staging via global_load_lds with XOR-swizzled SOURCE (LDS dest linear).
// AF32: A is raw f32 staged untouched into LDS (16B-chunk swizzle c16^row&15);
//       fragments convert f32->bf16 at ds_read time (packed cvt on VALU pipe).
// else: A bf16, 8-elem-chunk swizzle (chunk^row&7). B always bf16.
// Double-buffered, 1 barrier per K-iter. LDS: AF32 48KB (3 blk/CU),
// bf16 32KB (5 blk/CU).
// OUTMODE: 0 = f32 row-major, 1 = bf16 row-major, 2 = bf16 per-head planar
//          (value layout: [h][row][32ch], plane stride LQ*32 elems)
// ---------------------------------------------------------------------------
template<int OUTMODE, bool AF32>
__device__ __forceinline__ void gemm_body(
    const void* __restrict__ Av, const unsigned short* __restrict__ Bt,
    const float* __restrict__ bias, void* __restrict__ Out,
    int M, int N, int r0, int c0,
    char* As, char* Bs)
{
    const int t    = threadIdx.x;
    const int lane = t & 63, wave = t >> 6;
    const int wr   = wave >> 1, wc = wave & 1;
    const int lrow = lane & 15, lgrp = lane >> 4;
    constexpr int ABUF = AF32 ? 16384 : 8192;

    f32x4 acc[2][2] = {{{}, {}}, {{}, {}}};

    auto stage = [&](int buf, int k0) {
        if constexpr (AF32) {
            // 4 rounds x 16 rows of f32 (256 B/row); source chunk pre-swizzled
#pragma unroll
            for (int r = 0; r < 4; ++r) {
                const int row = r * 16 + (t >> 4);
                const int c16 = (t & 15) ^ (row & 15);
                const float* g = (const float*)Av +
                                 (size_t)min(r0 + row, M - 1) * 256 + k0 + c16 * 4;
                gload_lds16(g, As + buf * ABUF + r * 4096 + wave * 1024);
            }
        } else {
#pragma unroll
            for (int r = 0; r < 2; ++r) {
                const int row   = r * 32 + (t >> 3);
                const int chunk = (t & 7) ^ (row & 7);
                const unsigned short* g = (const unsigned short*)Av +
                    (size_t)min(r0 + row, M - 1) * 256 + k0 + chunk * 8;
                gload_lds16(g, As + buf * ABUF + r * 4096 + wave * 1024);
            }
        }
#pragma unroll
        for (int r = 0; r < 2; ++r) {
            const int row   = r * 32 + (t >> 3);
            const int chunk = (t & 7) ^ (row & 7);
            const unsigned short* g = Bt + (size_t)(c0 + row) * 256 + k0 + chunk * 8;
            gload_lds16(g, Bs + buf * 8192 + r * 4096 + wave * 1024);
        }
    };

    auto compute = [&](int buf) {
#pragma unroll
        for (int kk = 0; kk < 2; ++kk) {
            const int g = kk * 4 + lgrp;
            bf16x8 a[2], b[2];
#pragma unroll
            for (int mi = 0; mi < 2; ++mi) {
                const int row = wr * 32 + mi * 16 + lrow;
                if constexpr (AF32) {
                    const char* base = As + buf * ABUF + row * 256;
                    const f32x4 lo = *(const f32x4*)(base + (((2*g+0) ^ (row & 15)) * 16));
                    const f32x4 hi = *(const f32x4*)(base + (((2*g+1) ^ (row & 15)) * 16));
                    a[mi] = cvt8(lo, hi);
                } else {
                    a[mi] = *(const bf16x8*)(As + buf * ABUF + row * 128 +
                                             ((g ^ (row & 7)) * 16));
                }
            }
#pragma unroll
            for (int nj = 0; nj < 2; ++nj) {
                const int row = wc * 32 + nj * 16 + lrow;
                b[nj] = *(const bf16x8*)(Bs + buf * 8192 + row * 128 +
                                         ((g ^ (row & 7)) * 16));
            }
#pragma unroll
            for (int mi = 0; mi < 2; ++mi)
#pragma unroll
                for (int nj = 0; nj < 2; ++nj)
                    acc[mi][nj] = __builtin_amdgcn_mfma_f32_16x16x32_bf16(
                        a[mi], b[nj], acc[mi][nj], 0, 0, 0);
        }
    };

    stage(0, 0);
    __syncthreads();
    int cur = 0;
#pragma unroll
    for (int it = 0; it < 3; ++it) {
        stage(cur ^ 1, (it + 1) * 64);
        compute(cur);
        __syncthreads();
        cur ^= 1;
    }
    compute(cur);

#pragma unroll
    for (int mi = 0; mi < 2; ++mi)
#pragma unroll
        for (int nj = 0; nj < 2; ++nj) {
            const int col = c0 + wc * 32 + nj * 16 + lrow;
            const float bb = bias[col];
#pragma unroll
            for (int j = 0; j < 4; ++j) {
                const int row = r0 + wr * 32 + mi * 16 + lgrp * 4 + j;
                if (row < M) {
                    const float v = acc[mi][nj][j] + bb;
                    if constexpr (OUTMODE == 0)
                        ((float*)Out)[(size_t)row * N + col] = v;
                    else if constexpr (OUTMODE == 1)
                        ((unsigned short*)Out)[(size_t)row * N + col] = f2bf(v);
                    else  // per-head planar: [h][row][ch]
                        ((unsigned short*)Out)[(size_t)(col >> 5) * (LQ * 32) +
                                               (size_t)row * 32 + (col & 31)] = f2bf(v);
                }
            }
        }
}

// fused value-proj (y<4, planar bf16 out) + off/attn-proj (y>=4, row-major
// bf16 out); A operands read directly as f32 (inflat / query)
__global__ __launch_bounds__(256)
void gemm_dual(const float* __restrict__ A0, const unsigned short* __restrict__ B0,
               const float* __restrict__ bias0, unsigned short* __restrict__ out0,
               const float* __restrict__ A1, const unsigned short* __restrict__ B1,
               const float* __restrict__ bias1, unsigned short* __restrict__ out1)
{
    __shared__ __align__(16) char As[2 * 64 * 256];   // f32: 32 KB
    __shared__ __align__(16) char Bs[2 * 64 * 128];   // bf16: 16 KB
    const int y  = blockIdx.y;
    const int r0 = blockIdx.x * 64;
    if (y < 4)
        gemm_body<2, true>(A0, B0, bias0, out0, LQ, 256, r0, y * 64, As, Bs);
    else
        gemm_body<1, true>(A1, B1, bias1, out1, LQ, 384, r0, (y - 4) * 64, As, Bs);
}

__global__ __launch_bounds__(256)
void gemm_f32out(const unsigned short* __restrict__ A, const unsigned short* __restrict__ Bt,
                 const float* __restrict__ bias, float* __restrict__ out)
{
    __shared__ __align__(16) char As[2 * 64 * 128];
    __shared__ __align__(16) char Bs[2 * 64 * 128];
    gemm_body<0, false>(A, Bt, bias, out, LQ, 256, blockIdx.x * 64, blockIdx.y * 64,
                        As, Bs);
}

// ---------------------------------------------------------------------------
// Fused softmax + deformable bilinear sampling. 2 queries per 256-thread block.
// XCD-chunked block swizzle (bijective, nwg=4250=8*531+2). value is per-head
// planar [h][LEN_IN][32ch] bf16 (64 B rows -> x-corner pairs share a 128 B
// L2 line).
// ---------------------------------------------------------------------------
__global__ __launch_bounds__(256)
void msda_sample(const unsigned short* __restrict__ value,   // planar bf16
                 const unsigned short* __restrict__ offattn, // (LQ,384) bf16
                 const float* __restrict__ refp,             // (LQ,4,2)
                 const int*   __restrict__ shapes,           // (4,2)
                 const int*   __restrict__ lstart,           // (4,)
                 unsigned short* __restrict__ msda)          // (LQ,256) bf16
{
    __shared__ int   s_off[2][128][5];   // byte offsets within head plane
    __shared__ float s_w[2][128][5];

    // bijective XCD-chunk swizzle: nwg=4250, q=531, r=2 (m204 variant)
    const int orig = blockIdx.x;
    const int xcd  = orig & 7, pos = orig >> 3;
    const int wgid = (xcd < 2 ? xcd * 532 : 1064 + (xcd - 2) * 531) + pos;

    const int t   = threadIdx.x;
    const int sub = t >> 7, tl = t & 127;
    const int q   = wgid * 2 + sub;

    {
        const int lp = tl & 15, l = lp >> 2;
        const int Hs = shapes[2 * l + 0];
        const int Ws = shapes[2 * l + 1];
        const int st = lstart[l];

        const unsigned oxy = *(const unsigned*)(offattn + (size_t)q * 384 + 2 * tl);
        const float ox = bf2f(oxy & 0xffffu);
        const float oy = bf2f(oxy >> 16);
        const float rx = refp[q * 8 + l * 2 + 0];
        const float ry = refp[q * 8 + l * 2 + 1];

        const float x = (rx + ox / (float)Ws) * (float)Ws - 0.5f;
        const float y = (ry + oy / (float)Hs) * (float)Hs - 0.5f;
        const float x0f = floorf(x), y0f = floorf(y);
        const float lw = x - x0f, lh = y - y0f;
        const int   x0 = (int)x0f, y0 = (int)y0f;

        const float logit = bf2f(offattn[(size_t)q * 384 + 256 + tl]);
        float m = logit;
        for (int s = 8; s >= 1; s >>= 1) m = fmaxf(m, __shfl_xor(m, s, 16));
        const float e = __expf(logit - m);
        float ssum = e;
        for (int s = 8; s >= 1; s >>= 1) ssum += __shfl_xor(ssum, s, 16);
        const float a = e / ssum;

#pragma unroll
        for (int corner = 0; corner < 4; ++corner) {
            const int dy = corner >> 1, dx = corner & 1;
            const int hc = y0 + dy, wc = x0 + dx;
            const bool valid = (hc >= 0) && (hc < Hs) && (wc >= 0) && (wc < Ws);
            const float wy = dy ? lh : (1.f - lh);
            const float wx = dx ? lw : (1.f - lw);
            const int hcc = min(max(hc, 0), Hs - 1);
            const int wcc = min(max(wc, 0), Ws - 1);
            s_off[sub][tl][corner] = (st + hcc * Ws + wcc) * 64;  // plane bytes
            s_w[sub][tl][corner]   = valid ? (wy * wx * a) : 0.f;
        }
    }
    __syncthreads();

    const int chunk = tl & 3, quarter = (tl >> 2) & 3, h = tl >> 4;
    const char* vb = (const char*)value + (size_t)h * (LQ * 64) + chunk * 16;
    float a0 = 0.f, a1 = 0.f, a2 = 0.f, a3 = 0.f;
    float a4 = 0.f, a5 = 0.f, a6 = 0.f, a7 = 0.f;
#pragma unroll
    for (int j = 0; j < 4; ++j) {
        const int c = h * 16 + quarter * 4 + j;
#pragma unroll
        for (int corner = 0; corner < 4; ++corner) {
            const float w  = s_w[sub][c][corner];
            const int   bo = s_off[sub][c][corner];
            const uint4 v = *(const uint4*)(vb + (size_t)(unsigned)bo);
            a0 = fmaf(w, bf2f(v.x & 0xffffu), a0);
            a1 = fmaf(w, bf2f(v.x >> 16), a1);
            a2 = fmaf(w, bf2f(v.y & 0xffffu), a2);
            a3 = fmaf(w, bf2f(v.y >> 16), a3);
            a4 = fmaf(w, bf2f(v.z & 0xffffu), a4);
            a5 = fmaf(w, bf2f(v.z >> 16), a5);
            a6 = fmaf(w, bf2f(v.w & 0xffffu), a6);
            a7 = fmaf(w, bf2f(v.w >> 16), a7);
        }
    }
    a0 += __shfl_xor(a0, 4); a0 += __shfl_xor(a0, 8);
    a1 += __shfl_xor(a1, 4); a1 += __shfl_xor(a1, 8);
    a2 += __shfl_xor(a2, 4); a2 += __shfl_xor(a2, 8);
    a3 += __shfl_xor(a3, 4); a3 += __shfl_xor(a3, 8);
    a4 += __shfl_xor(a4, 4); a4 += __shfl_xor(a4, 8);
    a5 += __shfl_xor(a5, 4); a5 += __shfl_xor(a5, 8);
    a6 += __shfl_xor(a6, 4); a6 += __shfl_xor(a6, 8);
    a7 += __shfl_xor(a7, 4); a7 += __shfl_xor(a7, 8);
    if (quarter == 0) {
        uint4 o;
        o.x = (unsigned)f2bf(a0) | ((unsigned)f2bf(a1) << 16);
        o.y = (unsigned)f2bf(a2) | ((unsigned)f2bf(a3) << 16);
        o.z = (unsigned)f2bf(a4) | ((unsigned)f2bf(a5) << 16);
        o.w = (unsigned)f2bf(a6) | ((unsigned)f2bf(a7) << 16);
        *(uint4*)(msda + (size_t)q * 256 + h * 32 + chunk * 8) = o;
    }
}

// ---------------------------------------------------------------------------
extern "C" void kernel_launch(void* const* d_in, const int* in_sizes, int n_in,
                              void* d_out, int out_size, void* d_ws, size_t ws_size,
                              hipStream_t stream)
{
    const float* query  = (const float*)d_in[0];
    const float* refp   = (const float*)d_in[1];
    const float* inflat = (const float*)d_in[2];
    const int*   shapes = (const int*)  d_in[3];
    const int*   lstart = (const int*)  d_in[4];
    const float* W_off  = (const float*)d_in[5];
    const float* b_off  = (const float*)d_in[6];
    const float* W_attn = (const float*)d_in[7];
    const float* b_attn = (const float*)d_in[8];
    const float* W_v    = (const float*)d_in[9];
    const float* b_v    = (const float*)d_in[10];
    const float* W_out  = (const float*)d_in[11];
    const float* b_out  = (const float*)d_in[12];

    float* out = (float*)d_out;
    char*  ws  = (char*)d_ws;

    size_t o = 0;
    unsigned short* Wv_t   = (unsigned short*)(ws + o); o += 131072;
    unsigned short* Wout_t = (unsigned short*)(ws + o); o += 131072;
    unsigned short* Wcat_t = (unsigned short*)(ws + o); o += 196608;
    float*          bcat   = (float*)         (ws + o); o += 1536;
    unsigned short* value  = (unsigned short*)(ws + o); o += (size_t)LQ * 256 * 2;
    unsigned short* offattn= (unsigned short*)(ws + o); o += (size_t)LQ * 384 * 2;
    unsigned short* msda   = (unsigned short*)(ws + o);

    prep_w<<<256, 256, 0, stream>>>(W_v, W_out, W_off, W_attn, b_off, b_attn,
                                    Wv_t, Wout_t, Wcat_t, bcat);

    gemm_dual<<<dim3(133, 10), 256, 0, stream>>>(inflat, Wv_t, b_v, value,
                                                 query, Wcat_t, bcat, offattn);

    msda_sample<<<4250, 256, 0, stream>>>(value, offattn, refp, shapes, lstart, msda);

    gemm_f32out<<<dim3(133, 4), 256, 0, stream>>>(msda, Wout_t, b_out, out);
}

// Round 10
// 53.834 us; speedup vs baseline: 1.1031x; 1.1031x over previous
//
#include <hip/hip_runtime.h>

#define LQ    8500
#define C_DIM 256

typedef __attribute__((ext_vector_type(8))) short bf16x8;
typedef __attribute__((ext_vector_type(4))) float f32x4;

__device__ __forceinline__ unsigned short f2bf(float x) {
    union { float f; unsigned u; } c; c.f = x;
    unsigned r = c.u + 0x7FFFu + ((c.u >> 16) & 1u);
    return (unsigned short)(r >> 16);
}
__device__ __forceinline__ float bf2f(unsigned us) {
    union { unsigned u; float f; } c; c.u = us << 16;
    return c.f;
}

__device__ __forceinline__ void gload_lds16(const void* g, void* l) {
    __builtin_amdgcn_global_load_lds(
        (const __attribute__((address_space(1))) unsigned int*)g,
        (__attribute__((address_space(3))) unsigned int*)l, 16, 0, 0);
}

// ---------------------------------------------------------------------------
// prep: bf16-convert query & inflat (vectorized); transpose+convert weights
// to [N][K] bf16; concat off/attn weights (384 cols) and biases.
// ---------------------------------------------------------------------------
__global__ __launch_bounds__(256)
void prep_all(const float* __restrict__ query, const float* __restrict__ inflat,
              const float* __restrict__ Wv,   const float* __restrict__ Wout,
              const float* __restrict__ Woff, const float* __restrict__ Wattn,
              const float* __restrict__ boff, const float* __restrict__ battn,
              unsigned short* __restrict__ qbf,  unsigned short* __restrict__ ibf,
              unsigned short* __restrict__ Wv_t, unsigned short* __restrict__ Wout_t,
              unsigned short* __restrict__ Wcat_t, float* __restrict__ bcat)
{
    const int NV = LQ * 256 / 8;              // 272000 vec8 chunks per matrix
    const int tid    = blockIdx.x * 256 + threadIdx.x;
    const int stride = gridDim.x * 256;

    for (int v = tid; v < 2 * NV; v += stride) {
        const float*    src = (v < NV) ? query + (size_t)v * 8 : inflat + (size_t)(v - NV) * 8;
        unsigned short* dst = (v < NV) ? qbf   + (size_t)v * 8 : ibf    + (size_t)(v - NV) * 8;
        const float4 f0 = ((const float4*)src)[0];
        const float4 f1 = ((const float4*)src)[1];
        bf16x8 o;
        o[0] = (short)f2bf(f0.x); o[1] = (short)f2bf(f0.y);
        o[2] = (short)f2bf(f0.z); o[3] = (short)f2bf(f0.w);
        o[4] = (short)f2bf(f1.x); o[5] = (short)f2bf(f1.y);
        o[6] = (short)f2bf(f1.z); o[7] = (short)f2bf(f1.w);
        *(bf16x8*)dst = o;
    }

    const int total = 65536 * 3 + 32768 + 384;
    for (int i = tid; i < total; i += stride) {
        if (i < 65536) {
            int k = i >> 8, n = i & 255;
            Wv_t[n * 256 + k] = f2bf(Wv[i]);
        } else if (i < 131072) {
            int j = i - 65536; int k = j >> 8, n = j & 255;
            Wout_t[n * 256 + k] = f2bf(Wout[j]);
        } else if (i < 196608) {
            int j = i - 131072; int k = j >> 8, n = j & 255;
            Wcat_t[n * 256 + k] = f2bf(Woff[j]);
        } else if (i < 229376) {
            int j = i - 196608; int k = j >> 7, n = j & 127;
            Wcat_t[(256 + n) * 256 + k] = f2bf(Wattn[j]);
        } else {
            int j = i - 229376;
            bcat[j] = (j < 256) ? boff[j] : battn[j - 256];
        }
    }
}

// ---------------------------------------------------------------------------
// MFMA GEMM body: Out[M x N] = A[M x 256] @ Bt^T + bias, Bt is [N][256] bf16.
// 64x64 tile, BK=64, 256 threads = 4 waves (2x2), each wave a 32x32 sub-tile.
// global_load_lds staging, XOR-swizzled source (LDS dest linear), swizzled
// ds_read_b128, double-buffered, 1 barrier per K-iter. LDS 32KB -> 5 blk/CU.
// OUTMODE: 0 = f32 row-major, 1 = bf16 row-major, 2 = bf16 per-head planar
//          (value layout: [h][row][32ch], plane stride LQ*32 elems)
// ---------------------------------------------------------------------------
template<int OUTMODE>
__device__ __forceinline__ void gemm_body(
    const unsigned short* __restrict__ A, const unsigned short* __restrict__ Bt,
    const float* __restrict__ bias, void* __restrict__ Out,
    int M, int N, int r0, int c0,
    char* As, char* Bs)   // each [2][64][64] bf16
{
    const int t    = threadIdx.x;
    const int lane = t & 63, wave = t >> 6;
    const int wr   = wave >> 1, wc = wave & 1;
    const int lrow = lane & 15, lgrp = lane >> 4;

    f32x4 acc[2][2] = {{{}, {}}, {{}, {}}};

    auto stage = [&](int buf, int k0) {
#pragma unroll
        for (int r = 0; r < 2; ++r) {
            const int row   = r * 32 + (t >> 3);
            const int chunk = (t & 7) ^ (row & 7);
            const unsigned short* g =
                A + (size_t)min(r0 + row, M - 1) * 256 + k0 + chunk * 8;
            gload_lds16(g, As + buf * 8192 + r * 4096 + wave * 1024);
        }
#pragma unroll
        for (int r = 0; r < 2; ++r) {
            const int row   = r * 32 + (t >> 3);
            const int chunk = (t & 7) ^ (row & 7);
            const unsigned short* g = Bt + (size_t)(c0 + row) * 256 + k0 + chunk * 8;
            gload_lds16(g, Bs + buf * 8192 + r * 4096 + wave * 1024);
        }
    };

    auto compute = [&](int buf) {
#pragma unroll
        for (int kk = 0; kk < 2; ++kk) {
            const int g = kk * 4 + lgrp;
            bf16x8 a[2], b[2];
#pragma unroll
            for (int mi = 0; mi < 2; ++mi) {
                const int row = wr * 32 + mi * 16 + lrow;
                a[mi] = *(const bf16x8*)(As + buf * 8192 + row * 128 +
                                         ((g ^ (row & 7)) * 16));
            }
#pragma unroll
            for (int nj = 0; nj < 2; ++nj) {
                const int row = wc * 32 + nj * 16 + lrow;
                b[nj] = *(const bf16x8*)(Bs + buf * 8192 + row * 128 +
                                         ((g ^ (row & 7)) * 16));
            }
#pragma unroll
            for (int mi = 0; mi < 2; ++mi)
#pragma unroll
                for (int nj = 0; nj < 2; ++nj)
                    acc[mi][nj] = __builtin_amdgcn_mfma_f32_16x16x32_bf16(
                        a[mi], b[nj], acc[mi][nj], 0, 0, 0);
        }
    };

    stage(0, 0);
    __syncthreads();
    int cur = 0;
#pragma unroll
    for (int it = 0; it < 3; ++it) {
        stage(cur ^ 1, (it + 1) * 64);
        compute(cur);
        __syncthreads();
        cur ^= 1;
    }
    compute(cur);

#pragma unroll
    for (int mi = 0; mi < 2; ++mi)
#pragma unroll
        for (int nj = 0; nj < 2; ++nj) {
            const int col = c0 + wc * 32 + nj * 16 + lrow;
            const float bb = bias[col];
#pragma unroll
            for (int j = 0; j < 4; ++j) {
                const int row = r0 + wr * 32 + mi * 16 + lgrp * 4 + j;
                if (row < M) {
                    const float v = acc[mi][nj][j] + bb;
                    if constexpr (OUTMODE == 0)
                        ((float*)Out)[(size_t)row * N + col] = v;
                    else if constexpr (OUTMODE == 1)
                        ((unsigned short*)Out)[(size_t)row * N + col] = f2bf(v);
                    else  // per-head planar: [h][row][ch]
                        ((unsigned short*)Out)[(size_t)(col >> 5) * (LQ * 32) +
                                               (size_t)row * 32 + (col & 31)] = f2bf(v);
                }
            }
        }
}

// fused value-proj (y<4, planar bf16) + off/attn-proj (y>=4, row-major bf16)
__global__ __launch_bounds__(256)
void gemm_dual(const unsigned short* __restrict__ A0, const unsigned short* __restrict__ B0,
               const float* __restrict__ bias0, unsigned short* __restrict__ out0,
               const unsigned short* __restrict__ A1, const unsigned short* __restrict__ B1,
               const float* __restrict__ bias1, unsigned short* __restrict__ out1)
{
    __shared__ __align__(16) char As[2 * 64 * 64 * 2];
    __shared__ __align__(16) char Bs[2 * 64 * 64 * 2];
    const int y  = blockIdx.y;
    const int r0 = blockIdx.x * 64;
    if (y < 4)
        gemm_body<2>(A0, B0, bias0, out0, LQ, 256, r0, y * 64, As, Bs);
    else
        gemm_body<1>(A1, B1, bias1, out1, LQ, 384, r0, (y - 4) * 64, As, Bs);
}

__global__ __launch_bounds__(256)
void gemm_f32out(const unsigned short* __restrict__ A, const unsigned short* __restrict__ Bt,
                 const float* __restrict__ bias, float* __restrict__ out)
{
    __shared__ __align__(16) char As[2 * 64 * 64 * 2];
    __shared__ __align__(16) char Bs[2 * 64 * 64 * 2];
    gemm_body<0>(A, Bt, bias, out, LQ, 256, blockIdx.x * 64, blockIdx.y * 64,
                 As, Bs);
}

// ---------------------------------------------------------------------------
// Fused softmax + deformable bilinear sampling — barrier-free, LDS-free.
// Each thread computes its own combo's (offset, weight) for 4 corners, then
// the gather phase pulls the quad's 4 combos via DPP quad_perm broadcasts
// (pure VALU, no LDS pipe, no __syncthreads). XCD-chunked block swizzle.
// value is per-head planar [h][LEN_IN][32ch] bf16 (64 B rows).
// ---------------------------------------------------------------------------
template<int J>
__device__ __forceinline__ void gather_j(const char* vb,
                                         const int* c_off, const float* c_w,
                                         float* a)
{
#pragma unroll
    for (int corner = 0; corner < 4; ++corner) {
        // broadcast lane (quad_base + J)'s offset/weight to the whole quad
        const int bo = __builtin_amdgcn_mov_dpp(c_off[corner], J * 0x55, 0xf, 0xf, 0);
        union { int i; float f; } uw;
        union { float f; int i; } sw; sw.f = c_w[corner];
        uw.i = __builtin_amdgcn_mov_dpp(sw.i, J * 0x55, 0xf, 0xf, 0);
        const float w = uw.f;
        const uint4 v = *(const uint4*)(vb + (size_t)(unsigned)bo);
        a[0] = fmaf(w, bf2f(v.x & 0xffffu), a[0]);
        a[1] = fmaf(w, bf2f(v.x >> 16), a[1]);
        a[2] = fmaf(w, bf2f(v.y & 0xffffu), a[2]);
        a[3] = fmaf(w, bf2f(v.y >> 16), a[3]);
        a[4] = fmaf(w, bf2f(v.z & 0xffffu), a[4]);
        a[5] = fmaf(w, bf2f(v.z >> 16), a[5]);
        a[6] = fmaf(w, bf2f(v.w & 0xffffu), a[6]);
        a[7] = fmaf(w, bf2f(v.w >> 16), a[7]);
    }
}

__global__ __launch_bounds__(256)
void msda_sample(const unsigned short* __restrict__ value,   // planar bf16
                 const unsigned short* __restrict__ offattn, // (LQ,384) bf16
                 const float* __restrict__ refp,             // (LQ,4,2)
                 const int*   __restrict__ shapes,           // (4,2)
                 const int*   __restrict__ lstart,           // (4,)
                 unsigned short* __restrict__ msda)          // (LQ,256) bf16
{
    // bijective XCD-chunk swizzle: nwg=4250, q=531, r=2 (m204 variant)
    const int orig = blockIdx.x;
    const int xcd  = orig & 7, pos = orig >> 3;
    const int wgid = (xcd < 2 ? xcd * 532 : 1064 + (xcd - 2) * 531) + pos;

    const int t   = threadIdx.x;
    const int sub = t >> 7, tl = t & 127;
    const int q   = wgid * 2 + sub;

    // ---- per-combo: softmax + 4 corner (plane byte-offset, weight) ----
    int   c_off[4];
    float c_w[4];
    {
        const int lp = tl & 15, l = lp >> 2;
        const int Hs = shapes[2 * l + 0];
        const int Ws = shapes[2 * l + 1];
        const int st = lstart[l];

        const unsigned oxy = *(const unsigned*)(offattn + (size_t)q * 384 + 2 * tl);
        const float ox = bf2f(oxy & 0xffffu);
        const float oy = bf2f(oxy >> 16);
        const float rx = refp[q * 8 + l * 2 + 0];
        const float ry = refp[q * 8 + l * 2 + 1];

        const float x = (rx + ox / (float)Ws) * (float)Ws - 0.5f;
        const float y = (ry + oy / (float)Hs) * (float)Hs - 0.5f;
        const float x0f = floorf(x), y0f = floorf(y);
        const float lw = x - x0f, lh = y - y0f;
        const int   x0 = (int)x0f, y0 = (int)y0f;

        const float logit = bf2f(offattn[(size_t)q * 384 + 256 + tl]);
        float m = logit;
        for (int s = 8; s >= 1; s >>= 1) m = fmaxf(m, __shfl_xor(m, s, 16));
        const float e = __expf(logit - m);
        float ssum = e;
        for (int s = 8; s >= 1; s >>= 1) ssum += __shfl_xor(ssum, s, 16);
        const float a = e / ssum;

#pragma unroll
        for (int corner = 0; corner < 4; ++corner) {
            const int dy = corner >> 1, dx = corner & 1;
            const int hc = y0 + dy, wc = x0 + dx;
            const bool valid = (hc >= 0) && (hc < Hs) && (wc >= 0) && (wc < Ws);
            const float wy = dy ? lh : (1.f - lh);
            const float wx = dx ? lw : (1.f - lw);
            const int hcc = min(max(hc, 0), Hs - 1);
            const int wcc = min(max(wc, 0), Ws - 1);
            c_off[corner] = (st + hcc * Ws + wcc) * 64;   // plane byte offset
            c_w[corner]   = valid ? (wy * wx * a) : 0.f;
        }
    }

    // ---- gather phase (same thread, quad-local data via DPP) ----
    const int chunk = tl & 3, quarter = (tl >> 2) & 3, h = tl >> 4;
    const char* vb = (const char*)value + (size_t)h * (LQ * 64) + chunk * 16;
    float a[8] = {0.f, 0.f, 0.f, 0.f, 0.f, 0.f, 0.f, 0.f};
    gather_j<0>(vb, c_off, c_w, a);
    gather_j<1>(vb, c_off, c_w, a);
    gather_j<2>(vb, c_off, c_w, a);
    gather_j<3>(vb, c_off, c_w, a);

#pragma unroll
    for (int i = 0; i < 8; ++i) {
        a[i] += __shfl_xor(a[i], 4);
        a[i] += __shfl_xor(a[i], 8);
    }
    if (quarter == 0) {
        uint4 o;
        o.x = (unsigned)f2bf(a[0]) | ((unsigned)f2bf(a[1]) << 16);
        o.y = (unsigned)f2bf(a[2]) | ((unsigned)f2bf(a[3]) << 16);
        o.z = (unsigned)f2bf(a[4]) | ((unsigned)f2bf(a[5]) << 16);
        o.w = (unsigned)f2bf(a[6]) | ((unsigned)f2bf(a[7]) << 16);
        *(uint4*)(msda + (size_t)q * 256 + h * 32 + chunk * 8) = o;
    }
}

// ---------------------------------------------------------------------------
extern "C" void kernel_launch(void* const* d_in, const int* in_sizes, int n_in,
                              void* d_out, int out_size, void* d_ws, size_t ws_size,
                              hipStream_t stream)
{
    const float* query  = (const float*)d_in[0];
    const float* refp   = (const float*)d_in[1];
    const float* inflat = (const float*)d_in[2];
    const int*   shapes = (const int*)  d_in[3];
    const int*   lstart = (const int*)  d_in[4];
    const float* W_off  = (const float*)d_in[5];
    const float* b_off  = (const float*)d_in[6];
    const float* W_attn = (const float*)d_in[7];
    const float* b_attn = (const float*)d_in[8];
    const float* W_v    = (const float*)d_in[9];
    const float* b_v    = (const float*)d_in[10];
    const float* W_out  = (const float*)d_in[11];
    const float* b_out  = (const float*)d_in[12];

    float* out = (float*)d_out;
    char*  ws  = (char*)d_ws;

    size_t o = 0;
    unsigned short* qbf    = (unsigned short*)(ws + o); o += (size_t)LQ * 256 * 2;
    unsigned short* ibf    = (unsigned short*)(ws + o); o += (size_t)LQ * 256 * 2;
    unsigned short* Wv_t   = (unsigned short*)(ws + o); o += 131072;
    unsigned short* Wout_t = (unsigned short*)(ws + o); o += 131072;
    unsigned short* Wcat_t = (unsigned short*)(ws + o); o += 196608;
    float*          bcat   = (float*)         (ws + o); o += 1536;
    unsigned short* value  = (unsigned short*)(ws + o); o += (size_t)LQ * 256 * 2;
    unsigned short* offattn= (unsigned short*)(ws + o); o += (size_t)LQ * 384 * 2;
    unsigned short* msda   = (unsigned short*)(ws + o);

    prep_all<<<1024, 256, 0, stream>>>(query, inflat, W_v, W_out, W_off, W_attn,
                                       b_off, b_attn, qbf, ibf,
                                       Wv_t, Wout_t, Wcat_t, bcat);

    gemm_dual<<<dim3(133, 10), 256, 0, stream>>>(ibf, Wv_t, b_v, value,
                                                 qbf, Wcat_t, bcat, offattn);

    msda_sample<<<4250, 256, 0, stream>>>(value, offattn, refp, shapes, lstart, msda);

    gemm_f32out<<<dim3(133, 4), 256, 0, stream>>>(msda, Wout_t, b_out, out);
}

// Round 11
// 50.554 us; speedup vs baseline: 1.1747x; 1.0649x over previous
//
#include <hip/hip_runtime.h>

#define LQ    8500
#define C_DIM 256

typedef __attribute__((ext_vector_type(8))) short bf16x8;
typedef __attribute__((ext_vector_type(4))) float f32x4;

__device__ __forceinline__ unsigned short f2bf(float x) {
    union { float f; unsigned u; } c; c.f = x;
    unsigned r = c.u + 0x7FFFu + ((c.u >> 16) & 1u);
    return (unsigned short)(r >> 16);
}
__device__ __forceinline__ float bf2f(unsigned us) {
    union { unsigned u; float f; } c; c.u = us << 16;
    return c.f;
}

__device__ __forceinline__ void gload_lds16(const void* g, void* l) {
    __builtin_amdgcn_global_load_lds(
        (const __attribute__((address_space(1))) unsigned int*)g,
        (__attribute__((address_space(3))) unsigned int*)l, 16, 0, 0);
}

// ---------------------------------------------------------------------------
// prep: bf16-convert query & inflat (vectorized); transpose+convert weights
// to [N][K] bf16; concat off/attn weights (384 cols) and biases.
// ---------------------------------------------------------------------------
__global__ __launch_bounds__(256)
void prep_all(const float* __restrict__ query, const float* __restrict__ inflat,
              const float* __restrict__ Wv,   const float* __restrict__ Wout,
              const float* __restrict__ Woff, const float* __restrict__ Wattn,
              const float* __restrict__ boff, const float* __restrict__ battn,
              unsigned short* __restrict__ qbf,  unsigned short* __restrict__ ibf,
              unsigned short* __restrict__ Wv_t, unsigned short* __restrict__ Wout_t,
              unsigned short* __restrict__ Wcat_t, float* __restrict__ bcat)
{
    const int NV = LQ * 256 / 8;              // 272000 vec8 chunks per matrix
    const int tid    = blockIdx.x * 256 + threadIdx.x;
    const int stride = gridDim.x * 256;

    for (int v = tid; v < 2 * NV; v += stride) {
        const float*    src = (v < NV) ? query + (size_t)v * 8 : inflat + (size_t)(v - NV) * 8;
        unsigned short* dst = (v < NV) ? qbf   + (size_t)v * 8 : ibf    + (size_t)(v - NV) * 8;
        const float4 f0 = ((const float4*)src)[0];
        const float4 f1 = ((const float4*)src)[1];
        bf16x8 o;
        o[0] = (short)f2bf(f0.x); o[1] = (short)f2bf(f0.y);
        o[2] = (short)f2bf(f0.z); o[3] = (short)f2bf(f0.w);
        o[4] = (short)f2bf(f1.x); o[5] = (short)f2bf(f1.y);
        o[6] = (short)f2bf(f1.z); o[7] = (short)f2bf(f1.w);
        *(bf16x8*)dst = o;
    }

    const int total = 65536 * 3 + 32768 + 384;
    for (int i = tid; i < total; i += stride) {
        if (i < 65536) {
            int k = i >> 8, n = i & 255;
            Wv_t[n * 256 + k] = f2bf(Wv[i]);
        } else if (i < 131072) {
            int j = i - 65536; int k = j >> 8, n = j & 255;
            Wout_t[n * 256 + k] = f2bf(Wout[j]);
        } else if (i < 196608) {
            int j = i - 131072; int k = j >> 8, n = j & 255;
            Wcat_t[n * 256 + k] = f2bf(Woff[j]);
        } else if (i < 229376) {
            int j = i - 196608; int k = j >> 7, n = j & 127;
            Wcat_t[(256 + n) * 256 + k] = f2bf(Wattn[j]);
        } else {
            int j = i - 229376;
            bcat[j] = (j < 256) ? boff[j] : battn[j - 256];
        }
    }
}

// ---------------------------------------------------------------------------
// MFMA GEMM body: Out[M x N] = A[M x 256] @ Bt^T + bias, Bt is [N][256] bf16.
// 64x64 tile, BK=64, 256 threads = 4 waves (2x2), each wave a 32x32 sub-tile.
// global_load_lds staging, XOR-swizzled source (LDS dest linear), swizzled
// ds_read_b128, double-buffered, 1 barrier per K-iter. LDS 32KB -> 5 blk/CU.
// OUTMODE: 0 = f32 row-major, 1 = bf16 row-major, 2 = bf16 per-head planar
//          (value layout: [h][row][32ch], plane stride LQ*32 elems)
// ---------------------------------------------------------------------------
template<int OUTMODE>
__device__ __forceinline__ void gemm_body(
    const unsigned short* __restrict__ A, const unsigned short* __restrict__ Bt,
    const float* __restrict__ bias, void* __restrict__ Out,
    int M, int N, int r0, int c0,
    char* As, char* Bs)   // each [2][64][64] bf16
{
    const int t    = threadIdx.x;
    const int lane = t & 63, wave = t >> 6;
    const int wr   = wave >> 1, wc = wave & 1;
    const int lrow = lane & 15, lgrp = lane >> 4;

    f32x4 acc[2][2] = {{{}, {}}, {{}, {}}};

    auto stage = [&](int buf, int k0) {
#pragma unroll
        for (int r = 0; r < 2; ++r) {
            const int row   = r * 32 + (t >> 3);
            const int chunk = (t & 7) ^ (row & 7);
            const unsigned short* g =
                A + (size_t)min(r0 + row, M - 1) * 256 + k0 + chunk * 8;
            gload_lds16(g, As + buf * 8192 + r * 4096 + wave * 1024);
        }
#pragma unroll
        for (int r = 0; r < 2; ++r) {
            const int row   = r * 32 + (t >> 3);
            const int chunk = (t & 7) ^ (row & 7);
            const unsigned short* g = Bt + (size_t)(c0 + row) * 256 + k0 + chunk * 8;
            gload_lds16(g, Bs + buf * 8192 + r * 4096 + wave * 1024);
        }
    };

    auto compute = [&](int buf) {
#pragma unroll
        for (int kk = 0; kk < 2; ++kk) {
            const int g = kk * 4 + lgrp;
            bf16x8 a[2], b[2];
#pragma unroll
            for (int mi = 0; mi < 2; ++mi) {
                const int row = wr * 32 + mi * 16 + lrow;
                a[mi] = *(const bf16x8*)(As + buf * 8192 + row * 128 +
                                         ((g ^ (row & 7)) * 16));
            }
#pragma unroll
            for (int nj = 0; nj < 2; ++nj) {
                const int row = wc * 32 + nj * 16 + lrow;
                b[nj] = *(const bf16x8*)(Bs + buf * 8192 + row * 128 +
                                         ((g ^ (row & 7)) * 16));
            }
#pragma unroll
            for (int mi = 0; mi < 2; ++mi)
#pragma unroll
                for (int nj = 0; nj < 2; ++nj)
                    acc[mi][nj] = __builtin_amdgcn_mfma_f32_16x16x32_bf16(
                        a[mi], b[nj], acc[mi][nj], 0, 0, 0);
        }
    };

    stage(0, 0);
    __syncthreads();
    int cur = 0;
#pragma unroll
    for (int it = 0; it < 3; ++it) {
        stage(cur ^ 1, (it + 1) * 64);
        compute(cur);
        __syncthreads();
        cur ^= 1;
    }
    compute(cur);

#pragma unroll
    for (int mi = 0; mi < 2; ++mi)
#pragma unroll
        for (int nj = 0; nj < 2; ++nj) {
            const int col = c0 + wc * 32 + nj * 16 + lrow;
            const float bb = bias[col];
#pragma unroll
            for (int j = 0; j < 4; ++j) {
                const int row = r0 + wr * 32 + mi * 16 + lgrp * 4 + j;
                if (row < M) {
                    const float v = acc[mi][nj][j] + bb;
                    if constexpr (OUTMODE == 0)
                        ((float*)Out)[(size_t)row * N + col] = v;
                    else if constexpr (OUTMODE == 1)
                        ((unsigned short*)Out)[(size_t)row * N + col] = f2bf(v);
                    else  // per-head planar: [h][row][ch]
                        ((unsigned short*)Out)[(size_t)(col >> 5) * (LQ * 32) +
                                               (size_t)row * 32 + (col & 31)] = f2bf(v);
                }
            }
        }
}

// fused value-proj (c<4, planar bf16) + off/attn-proj (c>=4, row-major bf16).
// 1D grid 1330 = 133 row-tiles x 10 col-tiles, row-major in wgid, XCD-chunked
// (bijective m204: nwg=1330=8*166+2) so a row-tile's 10 col-blocks share one
// XCD's L2 -> A-tile staged from L2, not L3.
__global__ __launch_bounds__(256)
void gemm_dual(const unsigned short* __restrict__ A0, const unsigned short* __restrict__ B0,
               const float* __restrict__ bias0, unsigned short* __restrict__ out0,
               const unsigned short* __restrict__ A1, const unsigned short* __restrict__ B1,
               const float* __restrict__ bias1, unsigned short* __restrict__ out1)
{
    __shared__ __align__(16) char As[2 * 64 * 64 * 2];
    __shared__ __align__(16) char Bs[2 * 64 * 64 * 2];
    const int orig = blockIdx.x;
    const int xcd  = orig & 7, pos = orig >> 3;
    const int wgid = (xcd < 2 ? xcd * 167 : 334 + (xcd - 2) * 166) + pos;
    const int r0 = (wgid / 10) * 64;
    const int c  = wgid % 10;
    if (c < 4)
        gemm_body<2>(A0, B0, bias0, out0, LQ, 256, r0, c * 64, As, Bs);
    else
        gemm_body<1>(A1, B1, bias1, out1, LQ, 384, r0, (c - 4) * 64, As, Bs);
}

// out-GEMM: 1D grid 532 = 133 row-tiles x 4 col-tiles, XCD-chunked
// (nwg=532=8*66+4).
__global__ __launch_bounds__(256)
void gemm_f32out(const unsigned short* __restrict__ A, const unsigned short* __restrict__ Bt,
                 const float* __restrict__ bias, float* __restrict__ out)
{
    __shared__ __align__(16) char As[2 * 64 * 64 * 2];
    __shared__ __align__(16) char Bs[2 * 64 * 64 * 2];
    const int orig = blockIdx.x;
    const int xcd  = orig & 7, pos = orig >> 3;
    const int wgid = (xcd < 4 ? xcd * 67 : 268 + (xcd - 4) * 66) + pos;
    gemm_body<0>(A, Bt, bias, out, LQ, 256, (wgid >> 2) * 64, (wgid & 3) * 64,
                 As, Bs);
}

// ---------------------------------------------------------------------------
// Fused softmax + deformable bilinear sampling — barrier-free, LDS-free.
// Each thread computes its own combo's (offset, weight) for 4 corners, then
// the gather phase pulls the quad's 4 combos via DPP quad_perm broadcasts
// (pure VALU, no LDS pipe, no __syncthreads). XCD-chunked block swizzle.
// value is per-head planar [h][LEN_IN][32ch] bf16 (64 B rows).
// ---------------------------------------------------------------------------
template<int J>
__device__ __forceinline__ void gather_j(const char* vb,
                                         const int* c_off, const float* c_w,
                                         float* a)
{
#pragma unroll
    for (int corner = 0; corner < 4; ++corner) {
        // broadcast lane (quad_base + J)'s offset/weight to the whole quad
        const int bo = __builtin_amdgcn_mov_dpp(c_off[corner], J * 0x55, 0xf, 0xf, 0);
        union { int i; float f; } uw;
        union { float f; int i; } sw; sw.f = c_w[corner];
        uw.i = __builtin_amdgcn_mov_dpp(sw.i, J * 0x55, 0xf, 0xf, 0);
        const float w = uw.f;
        const uint4 v = *(const uint4*)(vb + (size_t)(unsigned)bo);
        a[0] = fmaf(w, bf2f(v.x & 0xffffu), a[0]);
        a[1] = fmaf(w, bf2f(v.x >> 16), a[1]);
        a[2] = fmaf(w, bf2f(v.y & 0xffffu), a[2]);
        a[3] = fmaf(w, bf2f(v.y >> 16), a[3]);
        a[4] = fmaf(w, bf2f(v.z & 0xffffu), a[4]);
        a[5] = fmaf(w, bf2f(v.z >> 16), a[5]);
        a[6] = fmaf(w, bf2f(v.w & 0xffffu), a[6]);
        a[7] = fmaf(w, bf2f(v.w >> 16), a[7]);
    }
}

__global__ __launch_bounds__(256)
void msda_sample(const unsigned short* __restrict__ value,   // planar bf16
                 const unsigned short* __restrict__ offattn, // (LQ,384) bf16
                 const float* __restrict__ refp,             // (LQ,4,2)
                 const int*   __restrict__ shapes,           // (4,2)
                 const int*   __restrict__ lstart,           // (4,)
                 unsigned short* __restrict__ msda)          // (LQ,256) bf16
{
    // bijective XCD-chunk swizzle: nwg=4250, q=531, r=2 (m204 variant)
    const int orig = blockIdx.x;
    const int xcd  = orig & 7, pos = orig >> 3;
    const int wgid = (xcd < 2 ? xcd * 532 : 1064 + (xcd - 2) * 531) + pos;

    const int t   = threadIdx.x;
    const int sub = t >> 7, tl = t & 127;
    const int q   = wgid * 2 + sub;

    // ---- per-combo: softmax + 4 corner (plane byte-offset, weight) ----
    int   c_off[4];
    float c_w[4];
    {
        const int lp = tl & 15, l = lp >> 2;
        const int Hs = shapes[2 * l + 0];
        const int Ws = shapes[2 * l + 1];
        const int st = lstart[l];

        const unsigned oxy = *(const unsigned*)(offattn + (size_t)q * 384 + 2 * tl);
        const float ox = bf2f(oxy & 0xffffu);
        const float oy = bf2f(oxy >> 16);
        const float rx = refp[q * 8 + l * 2 + 0];
        const float ry = refp[q * 8 + l * 2 + 1];

        const float x = (rx + ox / (float)Ws) * (float)Ws - 0.5f;
        const float y = (ry + oy / (float)Hs) * (float)Hs - 0.5f;
        const float x0f = floorf(x), y0f = floorf(y);
        const float lw = x - x0f, lh = y - y0f;
        const int   x0 = (int)x0f, y0 = (int)y0f;

        const float logit = bf2f(offattn[(size_t)q * 384 + 256 + tl]);
        float m = logit;
        for (int s = 8; s >= 1; s >>= 1) m = fmaxf(m, __shfl_xor(m, s, 16));
        const float e = __expf(logit - m);
        float ssum = e;
        for (int s = 8; s >= 1; s >>= 1) ssum += __shfl_xor(ssum, s, 16);
        const float a = e / ssum;

#pragma unroll
        for (int corner = 0; corner < 4; ++corner) {
            const int dy = corner >> 1, dx = corner & 1;
            const int hc = y0 + dy, wc = x0 + dx;
            const bool valid = (hc >= 0) && (hc < Hs) && (wc >= 0) && (wc < Ws);
            const float wy = dy ? lh : (1.f - lh);
            const float wx = dx ? lw : (1.f - lw);
            const int hcc = min(max(hc, 0), Hs - 1);
            const int wcc = min(max(wc, 0), Ws - 1);
            c_off[corner] = (st + hcc * Ws + wcc) * 64;   // plane byte offset
            c_w[corner]   = valid ? (wy * wx * a) : 0.f;
        }
    }

    // ---- gather phase (same thread, quad-local data via DPP) ----
    const int chunk = tl & 3, quarter = (tl >> 2) & 3, h = tl >> 4;
    const char* vb = (const char*)value + (size_t)h * (LQ * 64) + chunk * 16;
    float a[8] = {0.f, 0.f, 0.f, 0.f, 0.f, 0.f, 0.f, 0.f};
    gather_j<0>(vb, c_off, c_w, a);
    gather_j<1>(vb, c_off, c_w, a);
    gather_j<2>(vb, c_off, c_w, a);
    gather_j<3>(vb, c_off, c_w, a);

#pragma unroll
    for (int i = 0; i < 8; ++i) {
        a[i] += __shfl_xor(a[i], 4);
        a[i] += __shfl_xor(a[i], 8);
    }
    if (quarter == 0) {
        uint4 o;
        o.x = (unsigned)f2bf(a[0]) | ((unsigned)f2bf(a[1]) << 16);
        o.y = (unsigned)f2bf(a[2]) | ((unsigned)f2bf(a[3]) << 16);
        o.z = (unsigned)f2bf(a[4]) | ((unsigned)f2bf(a[5]) << 16);
        o.w = (unsigned)f2bf(a[6]) | ((unsigned)f2bf(a[7]) << 16);
        *(uint4*)(msda + (size_t)q * 256 + h * 32 + chunk * 8) = o;
    }
}

// ---------------------------------------------------------------------------
extern "C" void kernel_launch(void* const* d_in, const int* in_sizes, int n_in,
                              void* d_out, int out_size, void* d_ws, size_t ws_size,
                              hipStream_t stream)
{
    const float* query  = (const float*)d_in[0];
    const float* refp   = (const float*)d_in[1];
    const float* inflat = (const float*)d_in[2];
    const int*   shapes = (const int*)  d_in[3];
    const int*   lstart = (const int*)  d_in[4];
    const float* W_off  = (const float*)d_in[5];
    const float* b_off  = (const float*)d_in[6];
    const float* W_attn = (const float*)d_in[7];
    const float* b_attn = (const float*)d_in[8];
    const float* W_v    = (const float*)d_in[9];
    const float* b_v    = (const float*)d_in[10];
    const float* W_out  = (const float*)d_in[11];
    const float* b_out  = (const float*)d_in[12];

    float* out = (float*)d_out;
    char*  ws  = (char*)d_ws;

    size_t o = 0;
    unsigned short* qbf    = (unsigned short*)(ws + o); o += (size_t)LQ * 256 * 2;
    unsigned short* ibf    = (unsigned short*)(ws + o); o += (size_t)LQ * 256 * 2;
    unsigned short* Wv_t   = (unsigned short*)(ws + o); o += 131072;
    unsigned short* Wout_t = (unsigned short*)(ws + o); o += 131072;
    unsigned short* Wcat_t = (unsigned short*)(ws + o); o += 196608;
    float*          bcat   = (float*)         (ws + o); o += 1536;
    unsigned short* value  = (unsigned short*)(ws + o); o += (size_t)LQ * 256 * 2;
    unsigned short* offattn= (unsigned short*)(ws + o); o += (size_t)LQ * 384 * 2;
    unsigned short* msda   = (unsigned short*)(ws + o);

    prep_all<<<1024, 256, 0, stream>>>(query, inflat, W_v, W_out, W_off, W_attn,
                                       b_off, b_attn, qbf, ibf,
                                       Wv_t, Wout_t, Wcat_t, bcat);

    gemm_dual<<<1330, 256, 0, stream>>>(ibf, Wv_t, b_v, value,
                                        qbf, Wcat_t, bcat, offattn);

    msda_sample<<<4250, 256, 0, stream>>>(value, offattn, refp, shapes, lstart, msda);

    gemm_f32out<<<532, 256, 0, stream>>>(msda, Wout_t, b_out, out);
}

// Round 12
// 48.590 us; speedup vs baseline: 1.2221x; 1.0404x over previous
//
#include <hip/hip_runtime.h>

#define LQ    8500
#define C_DIM 256

typedef __attribute__((ext_vector_type(8))) short bf16x8;
typedef __attribute__((ext_vector_type(4))) float f32x4;

__device__ __forceinline__ unsigned short f2bf(float x) {
    union { float f; unsigned u; } c; c.f = x;
    unsigned r = c.u + 0x7FFFu + ((c.u >> 16) & 1u);
    return (unsigned short)(r >> 16);
}
__device__ __forceinline__ float bf2f(unsigned us) {
    union { unsigned u; float f; } c; c.u = us << 16;
    return c.f;
}

__device__ __forceinline__ void gload_lds16(const void* g, void* l) {
    __builtin_amdgcn_global_load_lds(
        (const __attribute__((address_space(1))) unsigned int*)g,
        (__attribute__((address_space(3))) unsigned int*)l, 16, 0, 0);
}

// ---------------------------------------------------------------------------
// prep: bf16-convert query & inflat (vectorized); transpose+convert weights
// to [N][K] bf16; concat off/attn weights (384 cols) and biases.
// ---------------------------------------------------------------------------
__global__ __launch_bounds__(256)
void prep_all(const float* __restrict__ query, const float* __restrict__ inflat,
              const float* __restrict__ Wv,   const float* __restrict__ Wout,
              const float* __restrict__ Woff, const float* __restrict__ Wattn,
              const float* __restrict__ boff, const float* __restrict__ battn,
              unsigned short* __restrict__ qbf,  unsigned short* __restrict__ ibf,
              unsigned short* __restrict__ Wv_t, unsigned short* __restrict__ Wout_t,
              unsigned short* __restrict__ Wcat_t, float* __restrict__ bcat)
{
    const int NV = LQ * 256 / 8;              // 272000 vec8 chunks per matrix
    const int tid    = blockIdx.x * 256 + threadIdx.x;
    const int stride = gridDim.x * 256;

    for (int v = tid; v < 2 * NV; v += stride) {
        const float*    src = (v < NV) ? query + (size_t)v * 8 : inflat + (size_t)(v - NV) * 8;
        unsigned short* dst = (v < NV) ? qbf   + (size_t)v * 8 : ibf    + (size_t)(v - NV) * 8;
        const float4 f0 = ((const float4*)src)[0];
        const float4 f1 = ((const float4*)src)[1];
        bf16x8 o;
        o[0] = (short)f2bf(f0.x); o[1] = (short)f2bf(f0.y);
        o[2] = (short)f2bf(f0.z); o[3] = (short)f2bf(f0.w);
        o[4] = (short)f2bf(f1.x); o[5] = (short)f2bf(f1.y);
        o[6] = (short)f2bf(f1.z); o[7] = (short)f2bf(f1.w);
        *(bf16x8*)dst = o;
    }

    const int total = 65536 * 3 + 32768 + 384;
    for (int i = tid; i < total; i += stride) {
        if (i < 65536) {
            int k = i >> 8, n = i & 255;
            Wv_t[n * 256 + k] = f2bf(Wv[i]);
        } else if (i < 131072) {
            int j = i - 65536; int k = j >> 8, n = j & 255;
            Wout_t[n * 256 + k] = f2bf(Wout[j]);
        } else if (i < 196608) {
            int j = i - 131072; int k = j >> 8, n = j & 255;
            Wcat_t[n * 256 + k] = f2bf(Woff[j]);
        } else if (i < 229376) {
            int j = i - 196608; int k = j >> 7, n = j & 127;
            Wcat_t[(256 + n) * 256 + k] = f2bf(Wattn[j]);
        } else {
            int j = i - 229376;
            bcat[j] = (j < 256) ? boff[j] : battn[j - 256];
        }
    }
}

// ---------------------------------------------------------------------------
// MFMA GEMM body (generic tile: 64 rows x (NJ*32) cols, BK=64, 256 threads =
// 4 waves as 2x2; each wave 32 rows x (NJ*16) cols). global_load_lds staging,
// XOR-swizzled source (LDS dest linear), swizzled ds_read_b128, double-
// buffered, 1 barrier per K-iter.
// NJ=2: 64x64 tile (As 8KB, Bs 8KB per buf). NJ=4: 64x128 (Bs 16KB per buf).
// OUTMODE: 0 = f32 row-major, 1 = bf16 row-major, 2 = bf16 per-head planar
//          (value layout: [h][row][32ch], plane stride LQ*32 elems)
// ---------------------------------------------------------------------------
template<int OUTMODE, int NJ>
__device__ __forceinline__ void gemm_body(
    const unsigned short* __restrict__ A, const unsigned short* __restrict__ Bt,
    const float* __restrict__ bias, void* __restrict__ Out,
    int M, int N, int r0, int c0,
    char* As, char* Bs)
{
    const int t    = threadIdx.x;
    const int lane = t & 63, wave = t >> 6;
    const int wr   = wave >> 1, wc = wave & 1;
    const int lrow = lane & 15, lgrp = lane >> 4;
    constexpr int BROWS = NJ * 32;            // B tile rows (cols of Out)
    constexpr int BBUF  = BROWS * 128;        // bytes per B buffer

    f32x4 acc[2][NJ] = {};

    auto stage = [&](int buf, int k0) {
#pragma unroll
        for (int r = 0; r < 2; ++r) {
            const int row   = r * 32 + (t >> 3);
            const int chunk = (t & 7) ^ (row & 7);
            const unsigned short* g =
                A + (size_t)min(r0 + row, M - 1) * 256 + k0 + chunk * 8;
            gload_lds16(g, As + buf * 8192 + r * 4096 + wave * 1024);
        }
#pragma unroll
        for (int r = 0; r < BROWS / 32; ++r) {
            const int row   = r * 32 + (t >> 3);
            const int chunk = (t & 7) ^ (row & 7);
            const unsigned short* g = Bt + (size_t)(c0 + row) * 256 + k0 + chunk * 8;
            gload_lds16(g, Bs + buf * BBUF + r * 4096 + wave * 1024);
        }
    };

    auto compute = [&](int buf) {
#pragma unroll
        for (int kk = 0; kk < 2; ++kk) {
            const int g = kk * 4 + lgrp;
            bf16x8 a[2], b[NJ];
#pragma unroll
            for (int mi = 0; mi < 2; ++mi) {
                const int row = wr * 32 + mi * 16 + lrow;
                a[mi] = *(const bf16x8*)(As + buf * 8192 + row * 128 +
                                         ((g ^ (row & 7)) * 16));
            }
#pragma unroll
            for (int nj = 0; nj < NJ; ++nj) {
                const int row = wc * (NJ * 16) + nj * 16 + lrow;
                b[nj] = *(const bf16x8*)(Bs + buf * BBUF + row * 128 +
                                         ((g ^ (row & 7)) * 16));
            }
#pragma unroll
            for (int mi = 0; mi < 2; ++mi)
#pragma unroll
                for (int nj = 0; nj < NJ; ++nj)
                    acc[mi][nj] = __builtin_amdgcn_mfma_f32_16x16x32_bf16(
                        a[mi], b[nj], acc[mi][nj], 0, 0, 0);
        }
    };

    stage(0, 0);
    __syncthreads();
    int cur = 0;
#pragma unroll
    for (int it = 0; it < 3; ++it) {
        stage(cur ^ 1, (it + 1) * 64);
        compute(cur);
        __syncthreads();
        cur ^= 1;
    }
    compute(cur);

#pragma unroll
    for (int mi = 0; mi < 2; ++mi)
#pragma unroll
        for (int nj = 0; nj < NJ; ++nj) {
            const int col = c0 + wc * (NJ * 16) + nj * 16 + lrow;
            const float bb = bias[col];
#pragma unroll
            for (int j = 0; j < 4; ++j) {
                const int row = r0 + wr * 32 + mi * 16 + lgrp * 4 + j;
                if (row < M) {
                    const float v = acc[mi][nj][j] + bb;
                    if constexpr (OUTMODE == 0)
                        ((float*)Out)[(size_t)row * N + col] = v;
                    else if constexpr (OUTMODE == 1)
                        ((unsigned short*)Out)[(size_t)row * N + col] = f2bf(v);
                    else  // per-head planar: [h][row][ch]
                        ((unsigned short*)Out)[(size_t)(col >> 5) * (LQ * 32) +
                                               (size_t)row * 32 + (col & 31)] = f2bf(v);
                }
            }
        }
}

// fused value-proj (c<2, planar bf16) + off/attn-proj (c>=2, row-major bf16).
// 64x128 tiles: 1D grid 665 = 133 row-tiles x 5 col-tiles, row-major in wgid,
// XCD-chunked (bijective: nwg=665=8*83+1) so a row-tile's 5 col-blocks share
// one XCD's L2 -> A-tile L2 re-reads halved vs 64x64.
__global__ __launch_bounds__(256)
void gemm_dual(const unsigned short* __restrict__ A0, const unsigned short* __restrict__ B0,
               const float* __restrict__ bias0, unsigned short* __restrict__ out0,
               const unsigned short* __restrict__ A1, const unsigned short* __restrict__ B1,
               const float* __restrict__ bias1, unsigned short* __restrict__ out1)
{
    __shared__ __align__(16) char As[2 * 64 * 64 * 2];    // 16 KB
    __shared__ __align__(16) char Bs[2 * 128 * 64 * 2];   // 32 KB
    const int orig = blockIdx.x;
    const int xcd  = orig & 7, pos = orig >> 3;
    const int wgid = (xcd == 0 ? 0 : 84 + (xcd - 1) * 83) + pos;
    const int r0 = (wgid / 5) * 64;
    const int c  = wgid % 5;
    if (c < 2)
        gemm_body<2, 4>(A0, B0, bias0, out0, LQ, 256, r0, c * 128, As, Bs);
    else
        gemm_body<1, 4>(A1, B1, bias1, out1, LQ, 384, r0, (c - 2) * 128, As, Bs);
}

// out-GEMM: 64x64 tiles, 1D grid 532 = 133 row-tiles x 4 col-tiles,
// XCD-chunked (nwg=532=8*66+4).
__global__ __launch_bounds__(256)
void gemm_f32out(const unsigned short* __restrict__ A, const unsigned short* __restrict__ Bt,
                 const float* __restrict__ bias, float* __restrict__ out)
{
    __shared__ __align__(16) char As[2 * 64 * 64 * 2];
    __shared__ __align__(16) char Bs[2 * 64 * 64 * 2];
    const int orig = blockIdx.x;
    const int xcd  = orig & 7, pos = orig >> 3;
    const int wgid = (xcd < 4 ? xcd * 67 : 268 + (xcd - 4) * 66) + pos;
    gemm_body<0, 2>(A, Bt, bias, out, LQ, 256, (wgid >> 2) * 64, (wgid & 3) * 64,
                    As, Bs);
}

// ---------------------------------------------------------------------------
// Fused softmax + deformable bilinear sampling — barrier-free, LDS-free.
// Each thread computes its own combo's (offset, weight) for 4 corners, then
// the gather phase pulls the quad's 4 combos via DPP quad_perm broadcasts
// (pure VALU, no LDS pipe, no __syncthreads). XCD-chunked block swizzle.
// value is per-head planar [h][LEN_IN][32ch] bf16 (64 B rows).
// ---------------------------------------------------------------------------
template<int J>
__device__ __forceinline__ void gather_j(const char* vb,
                                         const int* c_off, const float* c_w,
                                         float* a)
{
#pragma unroll
    for (int corner = 0; corner < 4; ++corner) {
        // broadcast lane (quad_base + J)'s offset/weight to the whole quad
        const int bo = __builtin_amdgcn_mov_dpp(c_off[corner], J * 0x55, 0xf, 0xf, 0);
        union { int i; float f; } uw;
        union { float f; int i; } sw; sw.f = c_w[corner];
        uw.i = __builtin_amdgcn_mov_dpp(sw.i, J * 0x55, 0xf, 0xf, 0);
        const float w = uw.f;
        const uint4 v = *(const uint4*)(vb + (size_t)(unsigned)bo);
        a[0] = fmaf(w, bf2f(v.x & 0xffffu), a[0]);
        a[1] = fmaf(w, bf2f(v.x >> 16), a[1]);
        a[2] = fmaf(w, bf2f(v.y & 0xffffu), a[2]);
        a[3] = fmaf(w, bf2f(v.y >> 16), a[3]);
        a[4] = fmaf(w, bf2f(v.z & 0xffffu), a[4]);
        a[5] = fmaf(w, bf2f(v.z >> 16), a[5]);
        a[6] = fmaf(w, bf2f(v.w & 0xffffu), a[6]);
        a[7] = fmaf(w, bf2f(v.w >> 16), a[7]);
    }
}

__global__ __launch_bounds__(256)
void msda_sample(const unsigned short* __restrict__ value,   // planar bf16
                 const unsigned short* __restrict__ offattn, // (LQ,384) bf16
                 const float* __restrict__ refp,             // (LQ,4,2)
                 const int*   __restrict__ shapes,           // (4,2)
                 const int*   __restrict__ lstart,           // (4,)
                 unsigned short* __restrict__ msda)          // (LQ,256) bf16
{
    // bijective XCD-chunk swizzle: nwg=4250, q=531, r=2 (m204 variant)
    const int orig = blockIdx.x;
    const int xcd  = orig & 7, pos = orig >> 3;
    const int wgid = (xcd < 2 ? xcd * 532 : 1064 + (xcd - 2) * 531) + pos;

    const int t   = threadIdx.x;
    const int sub = t >> 7, tl = t & 127;
    const int q   = wgid * 2 + sub;

    // ---- per-combo: softmax + 4 corner (plane byte-offset, weight) ----
    int   c_off[4];
    float c_w[4];
    {
        const int lp = tl & 15, l = lp >> 2;
        const int Hs = shapes[2 * l + 0];
        const int Ws = shapes[2 * l + 1];
        const int st = lstart[l];

        const unsigned oxy = *(const unsigned*)(offattn + (size_t)q * 384 + 2 * tl);
        const float ox = bf2f(oxy & 0xffffu);
        const float oy = bf2f(oxy >> 16);
        const float rx = refp[q * 8 + l * 2 + 0];
        const float ry = refp[q * 8 + l * 2 + 1];

        const float x = (rx + ox / (float)Ws) * (float)Ws - 0.5f;
        const float y = (ry + oy / (float)Hs) * (float)Hs - 0.5f;
        const float x0f = floorf(x), y0f = floorf(y);
        const float lw = x - x0f, lh = y - y0f;
        const int   x0 = (int)x0f, y0 = (int)y0f;

        const float logit = bf2f(offattn[(size_t)q * 384 + 256 + tl]);
        float m = logit;
        for (int s = 8; s >= 1; s >>= 1) m = fmaxf(m, __shfl_xor(m, s, 16));
        const float e = __expf(logit - m);
        float ssum = e;
        for (int s = 8; s >= 1; s >>= 1) ssum += __shfl_xor(ssum, s, 16);
        const float a = e / ssum;

#pragma unroll
        for (int corner = 0; corner < 4; ++corner) {
            const int dy = corner >> 1, dx = corner & 1;
            const int hc = y0 + dy, wc = x0 + dx;
            const bool valid = (hc >= 0) && (hc < Hs) && (wc >= 0) && (wc < Ws);
            const float wy = dy ? lh : (1.f - lh);
            const float wx = dx ? lw : (1.f - lw);
            const int hcc = min(max(hc, 0), Hs - 1);
            const int wcc = min(max(wc, 0), Ws - 1);
            c_off[corner] = (st + hcc * Ws + wcc) * 64;   // plane byte offset
            c_w[corner]   = valid ? (wy * wx * a) : 0.f;
        }
    }

    // ---- gather phase (same thread, quad-local data via DPP) ----
    const int chunk = tl & 3, quarter = (tl >> 2) & 3, h = tl >> 4;
    const char* vb = (const char*)value + (size_t)h * (LQ * 64) + chunk * 16;
    float a[8] = {0.f, 0.f, 0.f, 0.f, 0.f, 0.f, 0.f, 0.f};
    gather_j<0>(vb, c_off, c_w, a);
    gather_j<1>(vb, c_off, c_w, a);
    gather_j<2>(vb, c_off, c_w, a);
    gather_j<3>(vb, c_off, c_w, a);

#pragma unroll
    for (int i = 0; i < 8; ++i) {
        a[i] += __shfl_xor(a[i], 4);
        a[i] += __shfl_xor(a[i], 8);
    }
    if (quarter == 0) {
        uint4 o;
        o.x = (unsigned)f2bf(a[0]) | ((unsigned)f2bf(a[1]) << 16);
        o.y = (unsigned)f2bf(a[2]) | ((unsigned)f2bf(a[3]) << 16);
        o.z = (unsigned)f2bf(a[4]) | ((unsigned)f2bf(a[5]) << 16);
        o.w = (unsigned)f2bf(a[6]) | ((unsigned)f2bf(a[7]) << 16);
        *(uint4*)(msda + (size_t)q * 256 + h * 32 + chunk * 8) = o;
    }
}

// ---------------------------------------------------------------------------
extern "C" void kernel_launch(void* const* d_in, const int* in_sizes, int n_in,
                              void* d_out, int out_size, void* d_ws, size_t ws_size,
                              hipStream_t stream)
{
    const float* query  = (const float*)d_in[0];
    const float* refp   = (const float*)d_in[1];
    const float* inflat = (const float*)d_in[2];
    const int*   shapes = (const int*)  d_in[3];
    const int*   lstart = (const int*)  d_in[4];
    const float* W_off  = (const float*)d_in[5];
    const float* b_off  = (const float*)d_in[6];
    const float* W_attn = (const float*)d_in[7];
    const float* b_attn = (const float*)d_in[8];
    const float* W_v    = (const float*)d_in[9];
    const float* b_v    = (const float*)d_in[10];
    const float* W_out  = (const float*)d_in[11];
    const float* b_out  = (const float*)d_in[12];

    float* out = (float*)d_out;
    char*  ws  = (char*)d_ws;

    size_t o = 0;
    unsigned short* qbf    = (unsigned short*)(ws + o); o += (size_t)LQ * 256 * 2;
    unsigned short* ibf    = (unsigned short*)(ws + o); o += (size_t)LQ * 256 * 2;
    unsigned short* Wv_t   = (unsigned short*)(ws + o); o += 131072;
    unsigned short* Wout_t = (unsigned short*)(ws + o); o += 131072;
    unsigned short* Wcat_t = (unsigned short*)(ws + o); o += 196608;
    float*          bcat   = (float*)         (ws + o); o += 1536;
    unsigned short* value  = (unsigned short*)(ws + o); o += (size_t)LQ * 256 * 2;
    unsigned short* offattn= (unsigned short*)(ws + o); o += (size_t)LQ * 384 * 2;
    unsigned short* msda   = (unsigned short*)(ws + o);

    prep_all<<<1024, 256, 0, stream>>>(query, inflat, W_v, W_out, W_off, W_attn,
                                       b_off, b_attn, qbf, ibf,
                                       Wv_t, Wout_t, Wcat_t, bcat);

    gemm_dual<<<665, 256, 0, stream>>>(ibf, Wv_t, b_v, value,
                                       qbf, Wcat_t, bcat, offattn);

    msda_sample<<<4250, 256, 0, stream>>>(value, offattn, refp, shapes, lstart, msda);

    gemm_f32out<<<532, 256, 0, stream>>>(msda, Wout_t, b_out, out);
}